// Round 1
// baseline (506.421 us; speedup 1.0000x reference)
//
#include <hip/hip_runtime.h>
#include <hip/hip_bf16.h>

typedef __attribute__((ext_vector_type(8))) short short8;
typedef __attribute__((ext_vector_type(4))) float f32x4;

typedef const __attribute__((address_space(1))) void* as1cv_t;
typedef __attribute__((address_space(3))) void* as3v_t;

__device__ __forceinline__ unsigned short f2bf(float f) {
    unsigned u = __float_as_uint(f);
    u += 0x7fffu + ((u >> 16) & 1u);   // round-to-nearest-even
    return (unsigned short)(u >> 16);
}

__device__ __forceinline__ float gelu_tanh_f(float x) {
    // 0.5*x*(1+tanh(0.7978845608*(x+0.044715*x^3)))
    float t = 0.7978845608028654f * (x + 0.044715f * x * x * x);
    float u = 2.0f * t;
    u = fminf(fmaxf(u, -30.0f), 30.0f);   // avoid exp overflow -> NaN
    float e = __expf(u);
    float th = (e - 1.0f) / (e + 1.0f);
    return 0.5f * x * (1.0f + th);
}

// ---------------- conversion: fp32 -> bf16, elementwise ----------------
__global__ void cvt_f32_to_bf16(const float* __restrict__ in,
                                unsigned short* __restrict__ out,
                                long long n) {
    long long i = (long long)blockIdx.x * blockDim.x + threadIdx.x;
    long long stride = (long long)gridDim.x * blockDim.x;
    const float4* in4 = (const float4*)in;
    ushort4* out4 = (ushort4*)out;
    long long n4 = n >> 2;
    for (long long j = i; j < n4; j += stride) {
        float4 v = in4[j];
        ushort4 o;
        o.x = f2bf(v.x); o.y = f2bf(v.y); o.z = f2bf(v.z); o.w = f2bf(v.w);
        out4[j] = o;
    }
}

// ---------- transpose + convert: in [E][R][C] fp32 -> out [E][C][R] bf16 ----------
__global__ void transpose_cvt(const float* __restrict__ in,
                              unsigned short* __restrict__ out,
                              int R, int C) {
    __shared__ float tile[32][33];  // +1 pad: conflict-free
    int e = blockIdx.z;
    int c0 = blockIdx.x * 32;
    int r0 = blockIdx.y * 32;
    const float* ine = in + (size_t)e * R * C;
    unsigned short* oute = out + (size_t)e * R * C;
    int tx = threadIdx.x, ty = threadIdx.y;  // 32 x 8
#pragma unroll
    for (int i = 0; i < 4; i++) {
        tile[ty + i * 8][tx] = ine[(size_t)(r0 + ty + i * 8) * C + (c0 + tx)];
    }
    __syncthreads();
#pragma unroll
    for (int i = 0; i < 4; i++) {
        oute[(size_t)(c0 + ty + i * 8) * R + (r0 + tx)] = f2bf(tile[tx][ty + i * 8]);
    }
}

// ---------------- GEMM: C[e] = A[e] (MxK) * Bt[e] (NxK)^T ----------------
// m97 structure: 128x128 tile, BK=32, 4 waves each 64x64 (4x4 of 16x16x32 MFMA),
// global_load_lds width=16 staging, 2 barriers per K-step.
__device__ __forceinline__ void gload_lds16(const unsigned short* g, unsigned short* l) {
    __builtin_amdgcn_global_load_lds((as1cv_t)g, (as3v_t)l, 16, 0, 0);
}

template <int DO_GELU>
__global__ __launch_bounds__(256, 2) void gemm_bt(
    const unsigned short* __restrict__ A,   // [E][M][K] bf16
    const unsigned short* __restrict__ Bt,  // [E][N][K] bf16
    void* __restrict__ Cout,                // [E][M][N] bf16 (gelu) or fp32
    int M, int N, int K, int blocks_n)
{
    int per_e = (M / 128) * (N / 128);
    int bid = blockIdx.x;
    int e  = bid / per_e;
    int t  = bid % per_e;
    int bm = t / blocks_n;
    int bn = t % blocks_n;

    const unsigned short* Ae = A  + (size_t)e * M * K;
    const unsigned short* Be = Bt + (size_t)e * N * K;

    __shared__ alignas(16) unsigned short As[128 * 32];
    __shared__ alignas(16) unsigned short Bs[128 * 32];

    int tid = threadIdx.x;
    int wid = tid >> 6;
    int lane = tid & 63;
    int wave_m = wid >> 1;   // 0..1
    int wave_n = wid & 1;    // 0..1

    // staging: each wave fills two 1KB LDS chunks of A and of B.
    // chunk c covers tile rows [16c, 16c+16), row-major [row][k], 64B/row.
    int c0 = wid * 2;
    int sub_row = lane >> 2;        // 0..15 within chunk
    int sub_k   = (lane & 3) * 8;   // 0,8,16,24

    const unsigned short* ga0 = Ae + (size_t)(bm * 128 + c0 * 16 + sub_row) * K + sub_k;
    const unsigned short* ga1 = ga0 + (size_t)16 * K;
    const unsigned short* gb0 = Be + (size_t)(bn * 128 + c0 * 16 + sub_row) * K + sub_k;
    const unsigned short* gb1 = gb0 + (size_t)16 * K;
    unsigned short* la0 = As + c0 * 512;
    unsigned short* la1 = As + (c0 + 1) * 512;
    unsigned short* lb0 = Bs + c0 * 512;
    unsigned short* lb1 = Bs + (c0 + 1) * 512;

    f32x4 acc[4][4];
    f32x4 zero = {0.0f, 0.0f, 0.0f, 0.0f};
#pragma unroll
    for (int i = 0; i < 4; i++)
#pragma unroll
        for (int j = 0; j < 4; j++) acc[i][j] = zero;

    // fragment read addresses: A lane layout row=(lane&15), k=(lane>>4)*8..+8
    const unsigned short* a_rd = As + (size_t)(wave_m * 64 + (lane & 15)) * 32 + (lane >> 4) * 8;
    const unsigned short* b_rd = Bs + (size_t)(wave_n * 64 + (lane & 15)) * 32 + (lane >> 4) * 8;

    for (int k0 = 0; k0 < K; k0 += 32) {
        gload_lds16(ga0 + k0, la0);
        gload_lds16(ga1 + k0, la1);
        gload_lds16(gb0 + k0, lb0);
        gload_lds16(gb1 + k0, lb1);
        __syncthreads();   // drains vmcnt -> LDS tiles ready

        short8 af[4], bf[4];
#pragma unroll
        for (int mi = 0; mi < 4; mi++)
            af[mi] = *(const short8*)(a_rd + mi * 16 * 32);
#pragma unroll
        for (int ni = 0; ni < 4; ni++)
            bf[ni] = *(const short8*)(b_rd + ni * 16 * 32);

#pragma unroll
        for (int mi = 0; mi < 4; mi++)
#pragma unroll
            for (int ni = 0; ni < 4; ni++)
                acc[mi][ni] = __builtin_amdgcn_mfma_f32_16x16x32_bf16(
                    af[mi], bf[ni], acc[mi][ni], 0, 0, 0);

        __syncthreads();   // protect LDS before next stage
    }

    // epilogue: C/D layout col=lane&15, row=(lane>>4)*4+j  [m89 verified]
    int row0 = bm * 128 + wave_m * 64 + ((lane >> 4) * 4);
    int col0 = bn * 128 + wave_n * 64 + (lane & 15);
    if (DO_GELU) {
        unsigned short* Ce = (unsigned short*)Cout + (size_t)e * M * N;
#pragma unroll
        for (int mi = 0; mi < 4; mi++)
#pragma unroll
            for (int ni = 0; ni < 4; ni++)
#pragma unroll
                for (int j = 0; j < 4; j++) {
                    int row = row0 + mi * 16 + j;
                    int col = col0 + ni * 16;
                    Ce[(size_t)row * N + col] = f2bf(gelu_tanh_f(acc[mi][ni][j]));
                }
    } else {
        float* Ce = (float*)Cout + (size_t)e * M * N;
#pragma unroll
        for (int mi = 0; mi < 4; mi++)
#pragma unroll
            for (int ni = 0; ni < 4; ni++)
#pragma unroll
                for (int j = 0; j < 4; j++) {
                    int row = row0 + mi * 16 + j;
                    int col = col0 + ni * 16;
                    Ce[(size_t)row * N + col] = acc[mi][ni][j];
                }
    }
}

extern "C" void kernel_launch(void* const* d_in, const int* in_sizes, int n_in,
                              void* d_out, int out_size, void* d_ws, size_t ws_size,
                              hipStream_t stream) {
    const float* x  = (const float*)d_in[0];   // [E][T][H]
    const float* w1 = (const float*)d_in[1];   // [E][H][F]
    const float* w2 = (const float*)d_in[2];   // [E][F][H]
    float* out = (float*)d_out;                // [E][T][H]

    const int E = 8, T = 2048, H = 1024, F = 4096;

    // workspace layout (bf16): x | w1^T | w2^T | h    (~288 MiB total)
    unsigned short* xb  = (unsigned short*)d_ws;
    unsigned short* w1t = xb  + (size_t)E * T * H;   // [E][F][H]
    unsigned short* w2t = w1t + (size_t)E * H * F;   // [E][H][F]
    unsigned short* hb  = w2t + (size_t)E * F * H;   // [E][T][F]

    cvt_f32_to_bf16<<<2048, 256, 0, stream>>>(x, xb, (long long)E * T * H);

    dim3 tb(32, 8);
    // w1 [E][H=1024][F=4096] -> w1t [E][F][H]
    transpose_cvt<<<dim3(F / 32, H / 32, E), tb, 0, stream>>>(w1, w1t, H, F);
    // w2 [E][F=4096][H=1024] -> w2t [E][H][F]
    transpose_cvt<<<dim3(H / 32, F / 32, E), tb, 0, stream>>>(w2, w2t, F, H);

    // GEMM1 + GELU: hb[e] = gelu(xb[e] @ w1[e]),  M=T, N=F, K=H
    {
        int M = T, N = F, K = H;
        int blocks = E * (M / 128) * (N / 128);
        gemm_bt<1><<<blocks, 256, 0, stream>>>(xb, w1t, hb, M, N, K, N / 128);
    }
    // GEMM2: out[e] = hb[e] @ w2[e],  M=T, N=H, K=F
    {
        int M = T, N = H, K = F;
        int blocks = E * (M / 128) * (N / 128);
        gemm_bt<0><<<blocks, 256, 0, stream>>>(hb, w2t, out, M, N, K, N / 128);
    }
}

// Round 2
// 414.921 us; speedup vs baseline: 1.2205x; 1.2205x over previous
//
#include <hip/hip_runtime.h>
#include <hip/hip_bf16.h>

typedef __attribute__((ext_vector_type(8))) short short8;
typedef __attribute__((ext_vector_type(4))) float f32x4;

typedef const __attribute__((address_space(1))) void* as1cv_t;
typedef __attribute__((address_space(3))) void* as3v_t;

__device__ __forceinline__ unsigned short f2bf(float f) {
    unsigned u = __float_as_uint(f);
    u += 0x7fffu + ((u >> 16) & 1u);   // round-to-nearest-even
    return (unsigned short)(u >> 16);
}

__device__ __forceinline__ float gelu_tanh_f(float x) {
    float t = 0.7978845608028654f * (x + 0.044715f * x * x * x);
    float u = 2.0f * t;
    u = fminf(fmaxf(u, -30.0f), 30.0f);
    float e = __expf(u);
    float th = (e - 1.0f) / (e + 1.0f);
    return 0.5f * x * (1.0f + th);
}

// ---------------- conversion: fp32 -> bf16, elementwise ----------------
__global__ void cvt_f32_to_bf16(const float* __restrict__ in,
                                unsigned short* __restrict__ out,
                                long long n) {
    long long i = (long long)blockIdx.x * blockDim.x + threadIdx.x;
    long long stride = (long long)gridDim.x * blockDim.x;
    const float4* in4 = (const float4*)in;
    ushort4* out4 = (ushort4*)out;
    long long n4 = n >> 2;
    for (long long j = i; j < n4; j += stride) {
        float4 v = in4[j];
        ushort4 o;
        o.x = f2bf(v.x); o.y = f2bf(v.y); o.z = f2bf(v.z); o.w = f2bf(v.w);
        out4[j] = o;
    }
}

// ---------- transpose + convert: in [E][R][C] fp32 -> out [E][C][R] bf16 ----------
__global__ void transpose_cvt(const float* __restrict__ in,
                              unsigned short* __restrict__ out,
                              int R, int C) {
    __shared__ float tile[32][33];
    int e = blockIdx.z;
    int c0 = blockIdx.x * 32;
    int r0 = blockIdx.y * 32;
    const float* ine = in + (size_t)e * R * C;
    unsigned short* oute = out + (size_t)e * R * C;
    int tx = threadIdx.x, ty = threadIdx.y;  // 32 x 8
#pragma unroll
    for (int i = 0; i < 4; i++) {
        tile[ty + i * 8][tx] = ine[(size_t)(r0 + ty + i * 8) * C + (c0 + tx)];
    }
    __syncthreads();
#pragma unroll
    for (int i = 0; i < 4; i++) {
        oute[(size_t)(c0 + ty + i * 8) * R + (r0 + tx)] = f2bf(tile[tx][ty + i * 8]);
    }
}

// =======================================================================
// 256x256 tile GEMM, BK=32, 3-deep LDS pipeline, counted vmcnt,
// XOR bank swizzle (read-side) with inverse-swizzled gload_lds source.
//   C[e] = A[e] (MxK) * Bt[e] (NxK)^T
// 8 waves (2M x 4N); per-wave 128x64 output = acc[8][4] of 16x16 frags.
// LDS: 3 bufs x (A 16KB + B 16KB) = 96 KiB.
// =======================================================================
__device__ __forceinline__ void gload16(const void* g, void* l) {
    __builtin_amdgcn_global_load_lds((as1cv_t)g, (as3v_t)l, 16, 0, 0);
}

template <int DO_GELU>
__global__ __launch_bounds__(512, 2) void gemm256(
    const unsigned short* __restrict__ A,   // [E][M][K] bf16
    const unsigned short* __restrict__ Bt,  // [E][N][K] bf16
    void* __restrict__ Cout,                // [E][M][N] bf16 (gelu) or fp32
    int M, int N, int K, int tiles_m, int per_e, int nwg)
{
    // T1: XCD swizzle — each XCD gets a contiguous chunk (nwg % 8 == 0)
    int bid = blockIdx.x;
    int gbid = (bid & 7) * (nwg >> 3) + (bid >> 3);
    int e  = gbid / per_e;
    int t  = gbid % per_e;
    int bn = t / tiles_m;   // bm fastest: consecutive blocks share the B panel
    int bm = t % tiles_m;

    const unsigned short* Ae = A  + (size_t)e * M * K + (size_t)bm * 256 * K;
    const unsigned short* Be = Bt + (size_t)e * N * K + (size_t)bn * 256 * K;

    __shared__ alignas(16) unsigned short lds[3 * 16384];  // 96 KiB
    char* ldsc = (char*)lds;

    int tid  = threadIdx.x;
    int wid  = tid >> 6;
    int lane = tid & 63;
    int wave_m = wid >> 2;   // 0..1 -> rows wave_m*128
    int wave_n = wid & 3;    // 0..3 -> cols wave_n*64

    // ---- staging addresses ----
    // LDS (linear): chunk c = wid*64 + lane (+512 for l=1); byte = c*16.
    // row = c>>2 (64B/row, BK=32 bf16). Read-side swizzle key = ((row>>1)&3)<<4,
    // so the SOURCE is inverse-swizzled: kb = ((c&3)<<4) ^ key(row).
    int c0 = wid * 64 + lane;
    int r0 = c0 >> 2;            // rows 0..127 (l=0)
    int r1 = r0 + 128;           // rows 128..255 (l=1); key identical (128%8==0... (r+128)>>1 ≡ r>>1 mod 4)
    int kb = ((c0 & 3) << 4) ^ (((r0 >> 1) & 3) << 4);
    const char* gA0 = (const char*)(Ae + (size_t)r0 * K) + kb;
    const char* gA1 = (const char*)(Ae + (size_t)r1 * K) + kb;
    const char* gB0 = (const char*)(Be + (size_t)r0 * K) + kb;
    const char* gB1 = (const char*)(Be + (size_t)r1 * K) + kb;

    // ---- fragment read offsets (bytes within a buffer) ----
    // A-frag m: row = wave_m*128 + m*16 + (lane&15), kbyte = (lane>>4)*16 ^ key(row)
    // key depends only on (lane&15) bits 1..2 -> lane-constant across m.
    int xk = (((lane & 15) >> 1) & 3) << 4;
    int a_off = (wave_m * 128 + (lane & 15)) * 64 + ((((lane >> 4) << 4)) ^ xk);
    int b_off = 16384 + (wave_n * 64 + (lane & 15)) * 64 + ((((lane >> 4) << 4)) ^ xk);

    f32x4 acc[8][4];
    f32x4 zero = {0.0f, 0.0f, 0.0f, 0.0f};
#pragma unroll
    for (int i = 0; i < 8; i++)
#pragma unroll
        for (int j = 0; j < 4; j++) acc[i][j] = zero;

    unsigned bufC = 0, bufN = 32768, bufS = 65536;
    int NT = K >> 5;

#define STAGE(dst) do { \
        gload16(gA0, ldsc + (dst) + (wid << 10)); \
        gload16(gA1, ldsc + (dst) + 8192 + (wid << 10)); \
        gload16(gB0, ldsc + (dst) + 16384 + (wid << 10)); \
        gload16(gB1, ldsc + (dst) + 24576 + (wid << 10)); \
        gA0 += 64; gA1 += 64; gB0 += 64; gB1 += 64; } while (0)

    // prologue: tiles 0,1 in flight; wait tile 0 only (counted)
    STAGE(bufC);
    STAGE(bufN);
    asm volatile("s_waitcnt vmcnt(4)" ::: "memory");
    __builtin_amdgcn_s_barrier();
    asm volatile("" ::: "memory");

    for (int kt = 0; kt < NT; ++kt) {
        bool more = (kt + 2) < NT;
        if (more) STAGE(bufS);   // tile kt+2 -> flies across the next barrier

        const char* pa = ldsc + bufC + a_off;
        const char* pb = ldsc + bufC + b_off;

        short8 bf[4], af[4];
#pragma unroll
        for (int n = 0; n < 4; ++n) bf[n] = *(const short8*)(pb + n * 1024);
#pragma unroll
        for (int m = 0; m < 4; ++m) af[m] = *(const short8*)(pa + m * 1024);
        __builtin_amdgcn_s_setprio(1);
#pragma unroll
        for (int m = 0; m < 4; ++m)
#pragma unroll
            for (int n = 0; n < 4; ++n)
                acc[m][n] = __builtin_amdgcn_mfma_f32_16x16x32_bf16(af[m], bf[n], acc[m][n], 0, 0, 0);
        __builtin_amdgcn_s_setprio(0);

#pragma unroll
        for (int m = 0; m < 4; ++m) af[m] = *(const short8*)(pa + (m + 4) * 1024);
        __builtin_amdgcn_s_setprio(1);
#pragma unroll
        for (int m = 0; m < 4; ++m)
#pragma unroll
            for (int n = 0; n < 4; ++n)
                acc[m + 4][n] = __builtin_amdgcn_mfma_f32_16x16x32_bf16(af[m], bf[n], acc[m + 4][n], 0, 0, 0);
        __builtin_amdgcn_s_setprio(0);

        // boundary: my ds_reads done (WAR), tile kt+1 resident (counted vmcnt),
        // tile kt+2's 4 loads stay in flight. Never vmcnt(0) in steady state.
        if (more) asm volatile("s_waitcnt vmcnt(4) lgkmcnt(0)" ::: "memory");
        else      asm volatile("s_waitcnt vmcnt(0) lgkmcnt(0)" ::: "memory");
        __builtin_amdgcn_sched_barrier(0);
        __builtin_amdgcn_s_barrier();
        asm volatile("" ::: "memory");

        unsigned tmp = bufC; bufC = bufN; bufN = bufS; bufS = tmp;
    }
#undef STAGE

    // epilogue: C/D layout col=lane&15, row=(lane>>4)*4+j
    int row0 = bm * 256 + wave_m * 128 + ((lane >> 4) << 2);
    int col0 = bn * 256 + wave_n * 64 + (lane & 15);
    if (DO_GELU) {
        unsigned short* Ce = (unsigned short*)Cout + (size_t)e * M * N;
#pragma unroll
        for (int m = 0; m < 8; ++m)
#pragma unroll
            for (int n = 0; n < 4; ++n)
#pragma unroll
                for (int j = 0; j < 4; ++j) {
                    int row = row0 + m * 16 + j;
                    int col = col0 + n * 16;
                    Ce[(size_t)row * N + col] = f2bf(gelu_tanh_f(acc[m][n][j]));
                }
    } else {
        float* Ce = (float*)Cout + (size_t)e * M * N;
#pragma unroll
        for (int m = 0; m < 8; ++m)
#pragma unroll
            for (int n = 0; n < 4; ++n)
#pragma unroll
                for (int j = 0; j < 4; ++j) {
                    int row = row0 + m * 16 + j;
                    int col = col0 + n * 16;
                    Ce[(size_t)row * N + col] = acc[m][n][j];
                }
    }
}

extern "C" void kernel_launch(void* const* d_in, const int* in_sizes, int n_in,
                              void* d_out, int out_size, void* d_ws, size_t ws_size,
                              hipStream_t stream) {
    const float* x  = (const float*)d_in[0];   // [E][T][H]
    const float* w1 = (const float*)d_in[1];   // [E][H][F]
    const float* w2 = (const float*)d_in[2];   // [E][F][H]
    float* out = (float*)d_out;                // [E][T][H]

    const int E = 8, T = 2048, H = 1024, F = 4096;

    // workspace (bf16): x | w1^T | w2^T | h   (~302 MiB)
    unsigned short* xb  = (unsigned short*)d_ws;
    unsigned short* w1t = xb  + (size_t)E * T * H;   // [E][F][H]
    unsigned short* w2t = w1t + (size_t)E * H * F;   // [E][H][F]
    unsigned short* hb  = w2t + (size_t)E * F * H;   // [E][T][F]

    cvt_f32_to_bf16<<<2048, 256, 0, stream>>>(x, xb, (long long)E * T * H);

    dim3 tb(32, 8);
    transpose_cvt<<<dim3(F / 32, H / 32, E), tb, 0, stream>>>(w1, w1t, H, F);
    transpose_cvt<<<dim3(H / 32, F / 32, E), tb, 0, stream>>>(w2, w2t, F, H);

    // GEMM1 + GELU: hb[e] = gelu(xb[e] @ w1[e]),  M=T=2048, N=F=4096, K=H=1024
    {
        int M = T, N = F, K = H;
        int tiles_m = M / 256, per_e = tiles_m * (N / 256);
        int nwg = E * per_e;   // 1024, %8==0
        gemm256<1><<<nwg, 512, 0, stream>>>(xb, w1t, hb, M, N, K, tiles_m, per_e, nwg);
    }
    // GEMM2: out[e] = hb[e] @ w2[e],  M=T=2048, N=H=1024, K=F=4096
    {
        int M = T, N = H, K = F;
        int tiles_m = M / 256, per_e = tiles_m * (N / 256);
        int nwg = E * per_e;   // 256, %8==0
        gemm256<0><<<nwg, 512, 0, stream>>>(hb, w2t, out, M, N, K, tiles_m, per_e, nwg);
    }
}

// Round 3
// 414.023 us; speedup vs baseline: 1.2232x; 1.0022x over previous
//
#include <hip/hip_runtime.h>
#include <hip/hip_bf16.h>

typedef __attribute__((ext_vector_type(8))) short short8;
typedef __attribute__((ext_vector_type(4))) float f32x4;

typedef const __attribute__((address_space(1))) void* as1cv_t;
typedef __attribute__((address_space(3))) void* as3v_t;

__device__ __forceinline__ unsigned short f2bf(float f) {
    unsigned u = __float_as_uint(f);
    u += 0x7fffu + ((u >> 16) & 1u);   // round-to-nearest-even
    return (unsigned short)(u >> 16);
}

__device__ __forceinline__ float gelu_tanh_f(float x) {
    float t = 0.7978845608028654f * (x + 0.044715f * x * x * x);
    float u = 2.0f * t;
    u = fminf(fmaxf(u, -30.0f), 30.0f);
    float e = __expf(u);
    float th = (e - 1.0f) / (e + 1.0f);
    return 0.5f * x * (1.0f + th);
}

// ---------------- conversion: fp32 -> bf16, elementwise ----------------
__global__ void cvt_f32_to_bf16(const float* __restrict__ in,
                                unsigned short* __restrict__ out,
                                long long n) {
    long long i = (long long)blockIdx.x * blockDim.x + threadIdx.x;
    long long stride = (long long)gridDim.x * blockDim.x;
    const float4* in4 = (const float4*)in;
    ushort4* out4 = (ushort4*)out;
    long long n4 = n >> 2;
    for (long long j = i; j < n4; j += stride) {
        float4 v = in4[j];
        ushort4 o;
        o.x = f2bf(v.x); o.y = f2bf(v.y); o.z = f2bf(v.z); o.w = f2bf(v.w);
        out4[j] = o;
    }
}

// ---- transpose + convert: in [E][R][C] fp32 -> out [E][C][R] bf16, 64x64 tiles ----
__global__ void transpose_cvt64(const float* __restrict__ in,
                                unsigned short* __restrict__ out,
                                int R, int C) {
    __shared__ float t[64][65];
    int e = blockIdx.z;
    int c0 = blockIdx.x * 64;
    int r0 = blockIdx.y * 64;
    const float* ine = in + (size_t)e * R * C;
    unsigned short* oute = out + (size_t)e * R * C;
    int tid = threadIdx.x;           // 256
    int lx = tid & 15, ly = tid >> 4;
#pragma unroll
    for (int i = 0; i < 4; i++) {
        float4 v = *(const float4*)(ine + (size_t)(r0 + ly + i * 16) * C + c0 + lx * 4);
        t[lx * 4 + 0][ly + i * 16] = v.x;
        t[lx * 4 + 1][ly + i * 16] = v.y;
        t[lx * 4 + 2][ly + i * 16] = v.z;
        t[lx * 4 + 3][ly + i * 16] = v.w;
    }
    __syncthreads();
#pragma unroll
    for (int i = 0; i < 4; i++) {
        int c = ly + i * 16;
        ushort4 o;
        o.x = f2bf(t[c][lx * 4 + 0]);
        o.y = f2bf(t[c][lx * 4 + 1]);
        o.z = f2bf(t[c][lx * 4 + 2]);
        o.w = f2bf(t[c][lx * 4 + 3]);
        *(ushort4*)(oute + (size_t)(c0 + c) * R + r0 + lx * 4) = o;
    }
}

// =======================================================================
// 256x256 tile GEMM, BK=32, 4-deep LDS ring (4 x 32KB), 2 phases per K-tile,
// counted vmcnt(4) at tile boundaries. Stage tile t+2 during tile t
// (slot freed at end of tile t-2 -> structurally WAR-safe).
//   C[e] = A[e] (MxK) * Bt[e] (NxK)^T
// 8 waves (2M x 4N); per-wave 128x64 output = acc[8][4] of 16x16 frags.
// =======================================================================
__device__ __forceinline__ void gload16(const void* g, void* l) {
    __builtin_amdgcn_global_load_lds((as1cv_t)g, (as3v_t)l, 16, 0, 0);
}

template <int DO_GELU>
__global__ __launch_bounds__(512, 2) void gemm256p(
    const unsigned short* __restrict__ A,   // [E][M][K] bf16
    const unsigned short* __restrict__ Bt,  // [E][N][K] bf16
    void* __restrict__ Cout,                // [E][M][N] bf16 (gelu) or fp32
    int M, int N, int K, int tiles_m, int per_e, int nwg)
{
    // T1: XCD swizzle (nwg % 8 == 0)
    int bid = blockIdx.x;
    int gbid = (bid & 7) * (nwg >> 3) + (bid >> 3);
    int e  = gbid / per_e;
    int t0_ = gbid % per_e;
    int bn = t0_ / tiles_m;   // bm fastest: consecutive blocks share the B panel
    int bm = t0_ % tiles_m;

    const unsigned short* Ae = A  + (size_t)e * M * K + (size_t)bm * 256 * K;
    const unsigned short* Be = Bt + (size_t)e * N * K + (size_t)bn * 256 * K;

    __shared__ alignas(16) unsigned short lds[4 * 16384];  // 128 KiB: 4 bufs x (A16K|B16K)
    char* ldsc = (char*)lds;

    int tid  = threadIdx.x;
    int wid  = tid >> 6;
    int lane = tid & 63;
    int wave_m = wid >> 2;   // 0..1 -> rows wave_m*128
    int wave_n = wid & 3;    // 0..3 -> cols wave_n*64

    // ---- staging addresses (identical scheme to verified r2 kernel) ----
    // chunk c = wid*64 + lane; 16B per chunk; row = c>>2 (64B/row).
    // read-side swizzle key = ((row>>1)&3)<<4; source pre-swizzled.
    int c0 = wid * 64 + lane;
    int r0 = c0 >> 2;
    int kb = ((c0 & 3) << 4) ^ (((r0 >> 1) & 3) << 4);
    const char* gA0 = (const char*)(Ae + (size_t)r0 * K) + kb;
    const char* gA1 = (const char*)(Ae + (size_t)(r0 + 128) * K) + kb;
    const char* gB0 = (const char*)(Be + (size_t)r0 * K) + kb;
    const char* gB1 = (const char*)(Be + (size_t)(r0 + 128) * K) + kb;
    int sA = wid << 10;   // wave-uniform LDS stage offset

    // ---- fragment read offsets (bytes within a buffer) ----
    int xk = (((lane & 15) >> 1) & 3) << 4;
    int a_off = (wave_m * 128 + (lane & 15)) * 64 + ((((lane >> 4) << 4)) ^ xk);
    int b_off = 16384 + (wave_n * 64 + (lane & 15)) * 64 + ((((lane >> 4) << 4)) ^ xk);

    f32x4 acc[8][4];
    f32x4 zero = {0.0f, 0.0f, 0.0f, 0.0f};
#pragma unroll
    for (int i = 0; i < 8; i++)
#pragma unroll
        for (int j = 0; j < 4; j++) acc[i][j] = zero;

    int NT = K >> 5;

#define STAGE_A(dst) do { \
        gload16(gA0, ldsc + (dst) + sA); \
        gload16(gA1, ldsc + (dst) + 8192 + sA); \
        gA0 += 64; gA1 += 64; } while (0)
#define STAGE_B(dst) do { \
        gload16(gB0, ldsc + (dst) + 16384 + sA); \
        gload16(gB1, ldsc + (dst) + 24576 + sA); \
        gB0 += 64; gB1 += 64; } while (0)

    // prologue: stage tiles 0,1; wait tile 0 (counted: tile 1's 4 stay in flight)
    STAGE_A(0); STAGE_B(0);
    STAGE_A(32768); STAGE_B(32768);
    asm volatile("s_waitcnt vmcnt(4)" ::: "memory");
    __builtin_amdgcn_s_barrier();
    asm volatile("" ::: "memory");

    for (int kt = 0; kt < NT; ++kt) {
        unsigned bufT = (unsigned)(kt & 3) * 32768u;
        unsigned bufS = (unsigned)((kt + 2) & 3) * 32768u;
        bool more = (kt + 2) < NT;

        const char* pa = ldsc + bufT + a_off;
        const char* pb = ldsc + bufT + b_off;

        // ---------------- phase 1: m0-3 x n0-3 ----------------
        short8 af[4], bf[4];
#pragma unroll
        for (int n = 0; n < 4; ++n) bf[n] = *(const short8*)(pb + n * 1024);
#pragma unroll
        for (int m = 0; m < 4; ++m) af[m] = *(const short8*)(pa + m * 1024);
        if (more) STAGE_A(bufS);
        __builtin_amdgcn_s_barrier();
        asm volatile("s_waitcnt lgkmcnt(0)" ::: "memory");
        __builtin_amdgcn_s_setprio(1);
#pragma unroll
        for (int m = 0; m < 4; ++m)
#pragma unroll
            for (int n = 0; n < 4; ++n)
                acc[m][n] = __builtin_amdgcn_mfma_f32_16x16x32_bf16(af[m], bf[n], acc[m][n], 0, 0, 0);
        __builtin_amdgcn_s_setprio(0);
        __builtin_amdgcn_s_barrier();

        // ---------------- phase 2: m4-7 x n0-3 ----------------
#pragma unroll
        for (int m = 0; m < 4; ++m) af[m] = *(const short8*)(pa + (m + 4) * 1024);
        if (more) STAGE_B(bufS);
        // boundary accounting: outstanding = tile(kt+1) 4 loads + tile(kt+2) 4 loads.
        // vmcnt(4) retires kt+1 (needed next iter), keeps kt+2 in flight.
        if (more)              asm volatile("s_waitcnt vmcnt(4)" ::: "memory");
        else if (kt + 1 < NT)  asm volatile("s_waitcnt vmcnt(0)" ::: "memory");
        __builtin_amdgcn_s_barrier();
        asm volatile("s_waitcnt lgkmcnt(0)" ::: "memory");
        __builtin_amdgcn_s_setprio(1);
#pragma unroll
        for (int m = 0; m < 4; ++m)
#pragma unroll
            for (int n = 0; n < 4; ++n)
                acc[m + 4][n] = __builtin_amdgcn_mfma_f32_16x16x32_bf16(af[m], bf[n], acc[m + 4][n], 0, 0, 0);
        __builtin_amdgcn_s_setprio(0);
        __builtin_amdgcn_s_barrier();
    }
#undef STAGE_A
#undef STAGE_B

    // epilogue: C/D layout col=lane&15, row=(lane>>4)*4+j
    int row0 = bm * 256 + wave_m * 128 + ((lane >> 4) << 2);
    int col0 = bn * 256 + wave_n * 64 + (lane & 15);
    if (DO_GELU) {
        unsigned short* Ce = (unsigned short*)Cout + (size_t)e * M * N;
#pragma unroll
        for (int m = 0; m < 8; ++m)
#pragma unroll
            for (int n = 0; n < 4; ++n)
#pragma unroll
                for (int j = 0; j < 4; ++j) {
                    int row = row0 + m * 16 + j;
                    int col = col0 + n * 16;
                    Ce[(size_t)row * N + col] = f2bf(gelu_tanh_f(acc[m][n][j]));
                }
    } else {
        float* Ce = (float*)Cout + (size_t)e * M * N;
#pragma unroll
        for (int m = 0; m < 8; ++m)
#pragma unroll
            for (int n = 0; n < 4; ++n)
#pragma unroll
                for (int j = 0; j < 4; ++j) {
                    int row = row0 + m * 16 + j;
                    int col = col0 + n * 16;
                    Ce[(size_t)row * N + col] = acc[m][n][j];
                }
    }
}

extern "C" void kernel_launch(void* const* d_in, const int* in_sizes, int n_in,
                              void* d_out, int out_size, void* d_ws, size_t ws_size,
                              hipStream_t stream) {
    const float* x  = (const float*)d_in[0];   // [E][T][H]
    const float* w1 = (const float*)d_in[1];   // [E][H][F]
    const float* w2 = (const float*)d_in[2];   // [E][F][H]
    float* out = (float*)d_out;                // [E][T][H]

    const int E = 8, T = 2048, H = 1024, F = 4096;

    // workspace (bf16): x | w1^T | w2^T | h   (~302 MiB)
    unsigned short* xb  = (unsigned short*)d_ws;
    unsigned short* w1t = xb  + (size_t)E * T * H;   // [E][F][H]
    unsigned short* w2t = w1t + (size_t)E * H * F;   // [E][H][F]
    unsigned short* hb  = w2t + (size_t)E * F * H;   // [E][T][F]

    cvt_f32_to_bf16<<<2048, 256, 0, stream>>>(x, xb, (long long)E * T * H);

    // w1 [E][H][F] -> w1t [E][F][H];  w2 [E][F][H] -> w2t [E][H][F]
    transpose_cvt64<<<dim3(F / 64, H / 64, E), 256, 0, stream>>>(w1, w1t, H, F);
    transpose_cvt64<<<dim3(H / 64, F / 64, E), 256, 0, stream>>>(w2, w2t, F, H);

    // GEMM1 + GELU: hb[e] = gelu(xb[e] @ w1[e]),  M=2048, N=4096, K=1024
    {
        int M = T, N = F, K = H;
        int tiles_m = M / 256, per_e = tiles_m * (N / 256);
        int nwg = E * per_e;   // 1024
        gemm256p<1><<<nwg, 512, 0, stream>>>(xb, w1t, hb, M, N, K, tiles_m, per_e, nwg);
    }
    // GEMM2: out[e] = hb[e] @ w2[e],  M=2048, N=1024, K=4096
    {
        int M = T, N = H, K = F;
        int tiles_m = M / 256, per_e = tiles_m * (N / 256);
        int nwg = E * per_e;   // 256
        gemm256p<0><<<nwg, 512, 0, stream>>>(hb, w2t, out, M, N, K, tiles_m, per_e, nwg);
    }
}